// Round 7
// baseline (2084.162 us; speedup 1.0000x reference)
//
#include <hip/hip_runtime.h>

typedef unsigned short u16;
typedef unsigned long long u64;
typedef __attribute__((ext_vector_type(8))) short bf8;
typedef __attribute__((ext_vector_type(4))) float fx4;

#define N_ENT   100000
#define N_EDGE  500000
#define N_TEST  131072
#define EDIM    200
#define AE_LD   224     // all_ent leading dim (200 valid + 24 zero pad)
#define NB_SCAN 391     // ceil(100000/256)

// ---------- helpers ----------
__device__ __forceinline__ u16 f2bf(float f) {
  union { float f; unsigned u; } c; c.f = f;
  return (u16)((c.u + 0x7FFFu + ((c.u >> 16) & 1u)) >> 16);  // RNE
}
__device__ __forceinline__ float bf2f(u16 h) {
  union { unsigned u; float f; } c; c.u = ((unsigned)h) << 16;
  return c.f;
}
// async global->LDS, 16B per lane; LDS dest = wave-uniform base + lane*16
__device__ __forceinline__ void gload16(const u16* g, u16* l) {
  __builtin_amdgcn_global_load_lds(
      (const __attribute__((address_space(1))) void*)g,
      (__attribute__((address_space(3))) void*)l, 16, 0, 0);
}

// ---------- generic bf16 MFMA GEMM: out = act(A @ B^T + bias) ----------
// m97 structure: unpadded LDS tiles, global_load_lds width-16 staging, 2-barrier K-loop.
// A contiguous [M,lda] (rows clamped at mClamp; clamped values store-guarded).
// act: 0 none | 1 tanh | 3 dot-vs-qbuf -> dotOut (atta) | 4 lrelu,dot-auxF -> dotOut (logit)
//      5 store lrelu(acc + bias + dotOut[row]*auxF[col])
#define BM 128
#define BN 128
#define BK 32

__global__ __launch_bounds__(256) void gemm_bf16(
    const u16* __restrict__ A, long lda,
    const u16* __restrict__ B, long ldb,
    u16* __restrict__ out, long ldOut,
    int K, int mClamp,
    int mValid, int nValid, int nStore,
    const float* __restrict__ bias, int act, float slope,
    const u16* __restrict__ qbuf, const float* __restrict__ auxF,
    float* __restrict__ dotOut)
{
  __shared__ __align__(16) u16 As[BM * BK];   // 8 KB, NO pad (DMA layout)
  __shared__ __align__(16) u16 Bs[BN * BK];
  const int tid  = threadIdx.x;
  const int wave = tid >> 6, lane = tid & 63;
  const int wr = (wave >> 1) * 64, wc = (wave & 1) * 64;
  const int fr = lane & 15, fq = lane >> 4;
  const long bm = (long)blockIdx.x * BM, bn = (long)blockIdx.y * BN;

  // staging: wave stages rows [wave*32, +32) of A and B as 2 chunks of 16 rows;
  // chunk = 64 lanes x 16B; lane i -> row +i/4, u16 col (i&3)*8.
  const int srow = wave * 32;
  const int kc = (lane & 3) * 8;
  long aoff[2], boff[2];
  #pragma unroll
  for (int h = 0; h < 2; ++h) {
    long gm = bm + srow + h * 16 + (lane >> 2);
    if (gm >= mClamp) gm = mClamp - 1;
    aoff[h] = gm * lda + kc;
    boff[h] = (bn + srow + h * 16 + (lane >> 2)) * ldb + kc;
  }

  fx4 zero4 = {0.f, 0.f, 0.f, 0.f};
  fx4 acc[4][4];
  #pragma unroll
  for (int i = 0; i < 4; ++i)
    #pragma unroll
    for (int j = 0; j < 4; ++j) acc[i][j] = zero4;

  for (int k0 = 0; k0 < K; k0 += BK) {
    __syncthreads();                     // prev tile's ds_reads done
    #pragma unroll
    for (int h = 0; h < 2; ++h) {
      gload16(A + aoff[h] + k0, &As[(srow + h * 16) * BK]);
      gload16(B + boff[h] + k0, &Bs[(srow + h * 16) * BK]);
    }
    __syncthreads();                     // staging complete (vmcnt drained)
    bf8 aF[4], bF[4];
    #pragma unroll
    for (int mt = 0; mt < 4; ++mt) aF[mt] = *(const bf8*)&As[(wr + mt * 16 + fr) * BK + fq * 8];
    #pragma unroll
    for (int nt = 0; nt < 4; ++nt) bF[nt] = *(const bf8*)&Bs[(wc + nt * 16 + fr) * BK + fq * 8];
    #pragma unroll
    for (int mt = 0; mt < 4; ++mt)
      #pragma unroll
      for (int nt = 0; nt < 4; ++nt)
        acc[mt][nt] = __builtin_amdgcn_mfma_f32_16x16x32_bf16(aF[mt], bF[nt], acc[mt][nt], 0, 0, 0);
  }

  // C/D layout: col=lane&15, row=(lane>>4)*4+reg  [m89-verified]
  if (act == 3 || act == 4) {
    #pragma unroll
    for (int mt = 0; mt < 4; ++mt) {
      #pragma unroll
      for (int r = 0; r < 4; ++r) {
        const long gm = bm + wr + mt * 16 + fq * 4 + r;
        float p = 0.f;
        #pragma unroll
        for (int nt = 0; nt < 4; ++nt) {
          const long gn = bn + wc + nt * 16 + fr;
          float v = acc[mt][nt][r] + bias[gn];
          if (act == 3) p += v * bf2f(qbuf[gm * 128 + gn]);
          else { v = (v >= 0.f) ? v : v * slope; p += v * auxF[gn]; }
        }
        p += __shfl_xor(p, 1, 64); p += __shfl_xor(p, 2, 64);
        p += __shfl_xor(p, 4, 64); p += __shfl_xor(p, 8, 64);
        if (fr == 0 && gm < mValid)
          atomicAdd(&dotOut[gm], (act == 3) ? p * 0.07071067811865475f : p);  // 1/sqrt(200)
      }
    }
    return;
  }

  #pragma unroll
  for (int mt = 0; mt < 4; ++mt) {
    #pragma unroll
    for (int r = 0; r < 4; ++r) {
      const long gm = bm + wr + mt * 16 + fq * 4 + r;
      if (gm >= mValid) continue;
      const float attaV = (act == 5) ? dotOut[gm] : 0.f;
      #pragma unroll
      for (int nt = 0; nt < 4; ++nt) {
        const long gn = bn + wc + nt * 16 + fr;
        if (gn >= nStore) continue;
        float v = 0.f;
        if (gn < nValid) {
          v = acc[mt][nt][r];
          if (bias) v += bias[gn];
          if (act == 1) v = tanhf(v);
          else if (act == 5) { v += attaV * auxF[gn]; v = (v >= 0.f) ? v : v * slope; }
        }
        out[gm * ldOut + gn] = f2bf(v);
      }
    }
  }
}

// ---------- sorted-CSR edge aggregation ----------
__global__ void hist_kernel(const int* __restrict__ ei, int* __restrict__ cnt) {
  int e = blockIdx.x * 256 + threadIdx.x;
  if (e < N_EDGE) atomicAdd(&cnt[ei[N_EDGE + e]], 1);
}
__global__ void scanA_kernel(const int* __restrict__ cnt, int* __restrict__ offs,
                             int* __restrict__ blockSums) {
  __shared__ int s[256];
  int gid = blockIdx.x * 256 + threadIdx.x;
  int v = (gid < N_ENT) ? cnt[gid] : 0;
  s[threadIdx.x] = v;
  __syncthreads();
  for (int off = 1; off < 256; off <<= 1) {
    int t = (threadIdx.x >= off) ? s[threadIdx.x - off] : 0;
    __syncthreads();
    s[threadIdx.x] += t;
    __syncthreads();
  }
  if (gid < N_ENT) offs[gid] = s[threadIdx.x] - v;
  if (threadIdx.x == 255) blockSums[blockIdx.x] = s[255];
}
__global__ void scanB_kernel(const int* __restrict__ blockSums, int* __restrict__ blockOffs) {
  __shared__ int s[512];
  int v = (threadIdx.x < NB_SCAN) ? blockSums[threadIdx.x] : 0;
  s[threadIdx.x] = v;
  __syncthreads();
  for (int off = 1; off < 512; off <<= 1) {
    int t = (threadIdx.x >= off) ? s[threadIdx.x - off] : 0;
    __syncthreads();
    s[threadIdx.x] += t;
    __syncthreads();
  }
  if (threadIdx.x < NB_SCAN) blockOffs[threadIdx.x] = s[threadIdx.x] - v;
}
__global__ void scanC_kernel(int* __restrict__ offs, const int* __restrict__ blockOffs) {
  int gid = blockIdx.x * 256 + threadIdx.x;
  if (gid < N_ENT) offs[gid] += blockOffs[blockIdx.x];
}
__global__ void place_kernel(const int* __restrict__ ei, const int* __restrict__ et,
                             const int* __restrict__ offs, int* __restrict__ cursor,
                             int* __restrict__ sortedSrc, int* __restrict__ sortedT) {
  int e = blockIdx.x * 256 + threadIdx.x;
  if (e >= N_EDGE) return;
  int dst = ei[N_EDGE + e];
  int pos = offs[dst] + atomicAdd(&cursor[dst], 1);
  sortedSrc[pos] = ei[e];
  sortedT[pos]   = et[e];
}
// wave-per-entity, float4: A1 row = [segsum(ent[src]-rel[t])*rsqrt(max(deg,1)) | ent_emb[r] | 0]
__global__ void agg_A1_kernel(const int* __restrict__ offs, const int* __restrict__ cnt,
                              const int* __restrict__ sortedSrc, const int* __restrict__ sortedT,
                              const float* __restrict__ ent_emb, const float* __restrict__ rel_emb,
                              u16* __restrict__ A1) {
  const int r = blockIdx.x * 4 + (threadIdx.x >> 6);
  if (r >= N_ENT) return;
  const int lane = threadIdx.x & 63;
  const int beg = offs[r], n = cnt[r];
  u16* row = A1 + (size_t)r * 416;
  if (lane < 50) {
    float4 a = {0.f, 0.f, 0.f, 0.f};
    for (int e = 0; e < n; ++e) {
      const int s = sortedSrc[beg + e], t = sortedT[beg + e];
      float4 x = ((const float4*)(ent_emb + (size_t)s * EDIM))[lane];
      float4 y = ((const float4*)(rel_emb + (size_t)t * EDIM))[lane];
      a.x += x.x - y.x; a.y += x.y - y.y; a.z += x.z - y.z; a.w += x.w - y.w;
    }
    const float nm = rsqrtf(fmaxf((float)n, 1.f));
    u64 p = (u64)f2bf(a.x * nm) | ((u64)f2bf(a.y * nm) << 16)
          | ((u64)f2bf(a.z * nm) << 32) | ((u64)f2bf(a.w * nm) << 48);
    *(u64*)(row + 4 * lane) = p;
    float4 e = ((const float4*)(ent_emb + (size_t)r * EDIM))[lane];
    u64 q = (u64)f2bf(e.x) | ((u64)f2bf(e.y) << 16)
          | ((u64)f2bf(e.z) << 32) | ((u64)f2bf(e.w) << 48);
    *(u64*)(row + 200 + 4 * lane) = q;
  }
  if (lane < 16) row[400 + lane] = 0;
}

// ---------- catb: contiguous [N_TEST][448] = [all_ent[te0] | all_ent[te1]] ----------
__global__ void catb_kernel(const u16* __restrict__ all_ent, const int* __restrict__ toTest,
                            u16* __restrict__ catb) {
  const int i = blockIdx.x * 4 + (threadIdx.x >> 6);
  const int lane = threadIdx.x & 63;
  const int t0 = toTest[2 * i], t1 = toTest[2 * i + 1];
  u16* row = catb + (size_t)i * 448;
  if (lane < 28)
    *(bf8*)(row + lane * 8) = *(const bf8*)(all_ent + (size_t)t0 * AE_LD + lane * 8);
  else if (lane < 56)
    *(bf8*)(row + 224 + (lane - 28) * 8) =
        *(const bf8*)(all_ent + (size_t)t1 * AE_LD + (lane - 28) * 8);
}

// ---------- builders / precomputes ----------
__global__ void build_B1T(const float* __restrict__ W, const float* __restrict__ W_loop,
                          u16* __restrict__ B1T)
{
  int idx = blockIdx.x * 256 + threadIdx.x;
  if (idx >= 256 * 416) return;
  int n = idx / 416, k = idx % 416;
  float v = 0.f;
  if (n < 200) {
    if (k < 200) v = W[k * 200 + n];
    else if (k < 400) v = W_loop[(k - 200) * 200 + n];
  }
  B1T[idx] = f2bf(v);
}
__global__ void all_rel_kernel(const float* __restrict__ rel_emb, const float* __restrict__ W_rel,
                               float* __restrict__ all_rel)
{
  int r = blockIdx.x, c = threadIdx.x;
  if (c >= 200) return;
  const float* re = rel_emb + r * 200;
  float a = 0.f;
  for (int k = 0; k < 200; ++k) a += re[k] * W_rel[k * 200 + c];
  all_rel[r * 200 + c] = a;
}
// PQ[sel][m][n] = sum_r all_rel[r][sel*100+m] * w1[401+r][n]
__global__ void pq_kernel(const float* __restrict__ all_rel, const float* __restrict__ w1,
                          float* __restrict__ PQ) {
  int idx = blockIdx.x * 256 + threadIdx.x;
  if (idx >= 2 * 100 * 2048) return;
  int n = idx & 2047, m = (idx >> 11) % 100, sel = idx / 204800;
  float a = 0.f;
  for (int r = 0; r < 474; ++r)
    a += all_rel[r * 200 + sel * 100 + m] * w1[(size_t)(401 + r) * 2048 + n];
  PQ[idx] = a;
}
// P2[sel][k][n] = sum_m trans_w[k][m] * PQ[sel][m][n]
__global__ void p2_kernel(const float* __restrict__ trans_w, const float* __restrict__ PQ,
                          float* __restrict__ P2) {
  int idx = blockIdx.x * 256 + threadIdx.x;
  if (idx >= 2 * 200 * 2048) return;
  int n = idx & 2047, k = (idx >> 11) % 200, sel = idx / 409600;
  const float* pq = PQ + sel * 204800;
  float a = 0.f;
  for (int m = 0; m < 100; ++m) a += trans_w[k * 100 + m] * pq[m * 2048 + n];
  P2[idx] = a;
}
// W1eff [2048][448] B-layout: k<200: w1[k][n]+P2h ; 224<=k<424: w1[200+kk][n]-P2t ; else 0
__global__ void w1eff_kernel(const float* __restrict__ w1, const float* __restrict__ P2,
                             u16* __restrict__ W1eff) {
  int idx = blockIdx.x * 256 + threadIdx.x;
  if (idx >= 2048 * 448) return;
  int n = idx / 448, k = idx % 448;
  float v = 0.f;
  if (k < 200) v = w1[(size_t)k * 2048 + n] + P2[(size_t)k * 2048 + n];
  else if (k >= 224 && k < 424) {
    int kk = k - 224;
    v = w1[(size_t)(200 + kk) * 2048 + n] - P2[409600 + (size_t)kk * 2048 + n];
  }
  W1eff[idx] = f2bf(v);
}
__global__ void b1eff_kernel(const float* __restrict__ b1, const float* __restrict__ trans_b,
                             const float* __restrict__ PQ, float* __restrict__ b1eff) {
  int n = blockIdx.x * 256 + threadIdx.x;
  if (n >= 2048) return;
  float a = b1[n];
  for (int m = 0; m < 100; ++m)
    a += trans_b[m] * (PQ[m * 2048 + n] - PQ[204800 + m * 2048 + n]);
  b1eff[n] = a;
}
// qw2T/kw2T [128][224] B-layout: row j, col k<200: sum_m trans_w[k][m]*{q,k}_w[m][j]
__global__ void qkw2_kernel(const float* __restrict__ trans_w, const float* __restrict__ q_w,
                            const float* __restrict__ k_w, u16* __restrict__ qw2T,
                            u16* __restrict__ kw2T) {
  int idx = blockIdx.x * 256 + threadIdx.x;
  if (idx >= 128 * 224) return;
  int j = idx / 224, k = idx % 224;
  float a = 0.f, b = 0.f;
  if (k < 200)
    for (int m = 0; m < 100; ++m) {
      float t = trans_w[k * 100 + m];
      a += t * q_w[m * 128 + j];
      b += t * k_w[m * 128 + j];
    }
  qw2T[idx] = f2bf(a);
  kw2T[idx] = f2bf(b);
}
__global__ void qkb2_kernel(const float* __restrict__ q_b, const float* __restrict__ k_b,
                            const float* __restrict__ trans_b, const float* __restrict__ q_w,
                            const float* __restrict__ k_w, float* __restrict__ qb2,
                            float* __restrict__ kb2) {
  int j = threadIdx.x;
  if (j >= 128) return;
  float a = q_b[j], b = k_b[j];
  for (int m = 0; m < 100; ++m) {
    a += trans_b[m] * q_w[m * 128 + j];
    b += trans_b[m] * k_w[m * 128 + j];
  }
  qb2[j] = a; kb2[j] = b;
}
__global__ void build_w2T(const float* __restrict__ w2, u16* __restrict__ w2T)
{
  long idx = (long)blockIdx.x * 256 + threadIdx.x;
  if (idx >= (long)512 * 2048) return;
  int n = (int)(idx / 2048), k = (int)(idx % 2048);
  w2T[idx] = f2bf(w2[(size_t)k * 512 + n]);
}
__global__ void sigmoid_kernel(const float* __restrict__ logit, const float* __restrict__ b3,
                               float* __restrict__ out) {
  int i = blockIdx.x * 256 + threadIdx.x;
  if (i >= N_TEST) return;
  out[i] = 1.f / (1.f + __expf(-(logit[i] + b3[0])));
}

// ---------- host ----------
extern "C" void kernel_launch(void* const* d_in, const int* in_sizes, int n_in,
                              void* d_out, int out_size, void* d_ws, size_t ws_size,
                              hipStream_t stream)
{
  (void)in_sizes; (void)n_in; (void)out_size;
  const int*   edge_index = (const int*)d_in[0];
  const int*   edge_type  = (const int*)d_in[1];
  const int*   toTest     = (const int*)d_in[2];
  const float* ent_emb    = (const float*)d_in[3];
  const float* rel_emb    = (const float*)d_in[4];
  const float* W          = (const float*)d_in[5];
  const float* W_loop     = (const float*)d_in[6];
  const float* W_rel      = (const float*)d_in[7];
  const float* trans_w    = (const float*)d_in[8];
  const float* trans_b    = (const float*)d_in[9];
  const float* q_w        = (const float*)d_in[10];
  const float* q_b        = (const float*)d_in[11];
  const float* k_w        = (const float*)d_in[12];
  const float* k_b        = (const float*)d_in[13];
  const float* w1         = (const float*)d_in[14];
  const float* b1         = (const float*)d_in[15];
  const float* w2         = (const float*)d_in[16];
  const float* b2         = (const float*)d_in[17];
  const float* w3         = (const float*)d_in[18];
  const float* b3         = (const float*)d_in[19];
  float* out = (float*)d_out;

  // ---- workspace layout (lifetime overlays) ----
  unsigned char* ws = (unsigned char*)d_ws;
  float* atta    = (float*)(ws + 0);            //   524,288
  float* logit   = (float*)(ws + 524288);       //   524,288
  float* allrel  = (float*)(ws + 1048576);      //   379,392 (474*200*4 pad)
  u16*   B1T     = (u16*)  (ws + 1427968);      //   212,992
  u16*   W1eff   = (u16*)  (ws + 1640960);      // 1,835,008 (2048*448*2)
  u16*   qw2T    = (u16*)  (ws + 3475968);      //    57,344
  u16*   kw2T    = (u16*)  (ws + 3533312);      //    57,344
  float* b1eff   = (float*)(ws + 3590656);      //     8,192
  float* qb2     = (float*)(ws + 3598848);      //     1,024 (pad)
  float* kb2     = (float*)(ws + 3599872);      //     1,024 (pad)
  u16*   w2T     = (u16*)  (ws + 3600896);      // 2,097,152
  const size_t X_base = 5698048;
  u16*   all_ent = (u16*)  (ws + X_base);                  // 44,800,000
  u16*   Qbuf    = (u16*)  (ws + X_base + 44800000);       // 33,554,432
  const size_t Y_base = 84052480;
  u16*   A1      = (u16*)  (ws + Y_base);       // 83,200,000 (dead after GEMM1)
  const size_t Z_base = 167252480;

  // Z scratch (dead after precomputes, before catb is written)
  int*   cnt       = (int*)  (ws + Z_base);
  int*   offs      = (int*)  (ws + Z_base + 400000);
  int*   cursor    = (int*)  (ws + Z_base + 800000);
  int*   blockSums = (int*)  (ws + Z_base + 1200000);
  int*   blockOffs = (int*)  (ws + Z_base + 1202048);
  int*   sortedSrc = (int*)  (ws + Z_base + 1204096);
  int*   sortedT   = (int*)  (ws + Z_base + 3204096);
  float* PQ        = (float*)(ws + Z_base + 5204096);   // 1,638,400
  float* P2        = (float*)(ws + Z_base + 6842496);   // 3,276,800 -> ends Z+10,119,296

  // catb overlays dead A1 + Z scratch: [Y_base, Y_base + 117,440,512)
  u16* catb = (u16*)(ws + Y_base);
  const size_t H_base = Y_base + (size_t)N_TEST * 448 * 2;   // 201,492,992

  int CH;
  if      (H_base + (size_t)131072 * 4096 <= ws_size) CH = 131072;
  else if (H_base + (size_t)65536  * 4096 <= ws_size) CH = 65536;
  else if (H_base + (size_t)32768  * 4096 <= ws_size) CH = 32768;
  else if (H_base + (size_t)16384  * 4096 <= ws_size) CH = 16384;
  else if (H_base + (size_t)8192   * 4096 <= ws_size) CH = 8192;
  else return;
  u16* h1 = (u16*)(ws + H_base);                 // CH*2048*2
  const int NC = N_TEST / CH;

  hipMemsetAsync(cnt, 0, 400000, stream);
  hipMemsetAsync(cursor, 0, 400000, stream);
  hipMemsetAsync(atta, 0, 524288, stream);
  hipMemsetAsync(logit, 0, 524288, stream);

  // phase 1: CSR aggregation -> A1
  hist_kernel<<<(N_EDGE + 255) / 256, 256, 0, stream>>>(edge_index, cnt);
  scanA_kernel<<<NB_SCAN, 256, 0, stream>>>(cnt, offs, blockSums);
  scanB_kernel<<<1, 512, 0, stream>>>(blockSums, blockOffs);
  scanC_kernel<<<NB_SCAN, 256, 0, stream>>>(offs, blockOffs);
  place_kernel<<<(N_EDGE + 255) / 256, 256, 0, stream>>>(edge_index, edge_type, offs, cursor,
                                                         sortedSrc, sortedT);
  agg_A1_kernel<<<(N_ENT + 3) / 4, 256, 0, stream>>>(offs, cnt, sortedSrc, sortedT,
                                                     ent_emb, rel_emb, A1);
  build_B1T<<<(256 * 416) / 256, 256, 0, stream>>>(W, W_loop, B1T);

  // all_ent = tanh([agg*norm | ent] @ [W ; W_loop]) -> bf16 [100000][224]
  gemm_bf16<<<dim3(782, 2), 256, 0, stream>>>(A1, 416, B1T, 416, all_ent, AE_LD,
      416, N_ENT, N_ENT, 200, AE_LD, nullptr, 1, 0.f, nullptr, nullptr, nullptr);

  // phase 2: folded-weight precomputes (f32; PQ/P2 die here)
  all_rel_kernel<<<474, 256, 0, stream>>>(rel_emb, W_rel, allrel);
  pq_kernel<<<(2 * 100 * 2048) / 256, 256, 0, stream>>>(allrel, w1, PQ);
  p2_kernel<<<(2 * 200 * 2048) / 256, 256, 0, stream>>>(trans_w, PQ, P2);
  w1eff_kernel<<<(2048 * 448) / 256, 256, 0, stream>>>(w1, P2, W1eff);
  b1eff_kernel<<<8, 256, 0, stream>>>(b1, trans_b, PQ, b1eff);
  qkw2_kernel<<<(128 * 224) / 256, 256, 0, stream>>>(trans_w, q_w, k_w, qw2T, kw2T);
  qkb2_kernel<<<1, 128, 0, stream>>>(q_b, k_b, trans_b, q_w, k_w, qb2, kb2);
  build_w2T<<<(512 * 2048) / 256, 256, 0, stream>>>(w2, w2T);

  // phase 3: contiguous gather, then atta = ((te0@qw2+qb2) . (te1@kw2+kb2)) / sqrt(200)
  catb_kernel<<<N_TEST / 4, 256, 0, stream>>>(all_ent, toTest, catb);
  gemm_bf16<<<dim3(1024, 1), 256, 0, stream>>>(catb, 448, qw2T, 224, Qbuf, 128,
      224, N_TEST, N_TEST, 128, 128, qb2, 0, 0.f, nullptr, nullptr, nullptr);
  gemm_bf16<<<dim3(1024, 1), 256, 0, stream>>>(catb + 224, 448, kw2T, 224, nullptr, 0,
      224, N_TEST, N_TEST, 128, 128, kb2, 3, 0.f, Qbuf, nullptr, atta);

  // phase 4: per-chunk  h1 = lrelu(catb @ W1eff + atta*w1[400,:] + b1eff)
  //          logit += rowdot(lrelu(h1 @ w2T + b2), w3)  ;  then sigmoid
  for (int c = 0; c < NC; ++c) {
    gemm_bf16<<<dim3(CH / 128, 16), 256, 0, stream>>>(catb + (size_t)c * CH * 448, 448,
        W1eff, 448, h1, 2048,
        448, CH, CH, 2048, 2048, b1eff, 5, 0.0001f,
        nullptr, w1 + (size_t)400 * 2048, atta + (size_t)c * CH);
    gemm_bf16<<<dim3(CH / 128, 4), 256, 0, stream>>>(h1, 2048, w2T, 2048, nullptr, 0,
        2048, CH, CH, 512, 512, b2, 4, 0.001f,
        nullptr, w3, logit + (size_t)c * CH);
  }
  sigmoid_kernel<<<N_TEST / 256, 256, 0, stream>>>(logit, b3, out);
}

// Round 8
// 1833.243 us; speedup vs baseline: 1.1369x; 1.1369x over previous
//
#include <hip/hip_runtime.h>

typedef unsigned short u16;
typedef unsigned long long u64;
typedef __attribute__((ext_vector_type(8))) short bf8;
typedef __attribute__((ext_vector_type(4))) float fx4;

#define N_ENT   100000
#define N_EDGE  500000
#define N_TEST  131072
#define EDIM    200
#define AE_LD   224     // all_ent leading dim (200 valid + 24 zero pad)
#define NB_SCAN 391     // ceil(100000/256)

// ---------- helpers ----------
__device__ __forceinline__ u16 f2bf(float f) {
  union { float f; unsigned u; } c; c.f = f;
  return (u16)((c.u + 0x7FFFu + ((c.u >> 16) & 1u)) >> 16);  // RNE
}
__device__ __forceinline__ float bf2f(u16 h) {
  union { unsigned u; float f; } c; c.u = ((unsigned)h) << 16;
  return c.f;
}
// async global->LDS, 16B per lane; LDS dest = wave-uniform base + lane*16
__device__ __forceinline__ void gload16(const u16* g, u16* l) {
  __builtin_amdgcn_global_load_lds(
      (const __attribute__((address_space(1))) void*)g,
      (__attribute__((address_space(3))) void*)l, 16, 0, 0);
}

// ---------- generic bf16 MFMA GEMM: out = act(A @ B^T + bias) ----------
// m97 structure + LDS-transposed vector-store epilogue.
// idxMode: 0 none (clamp at mClamp), 2 rowIdx[2*gm], 3 rowIdx[2*gm+1],
//          4 dual-gather: cols <224 from rowIdx[2*gm], cols >=224 from rowIdx[2*gm+1]
// act: 0 none | 1 tanh | 3 dot-vs-qbuf -> dotOut (atta) | 4 lrelu,dot-auxF -> dotOut (logit)
//      5 store lrelu(acc + bias + dotOut[row]*auxF[col])
#define BM 128
#define BN 128
#define BK 32
#define EPS 72   // epilogue LDS row stride (u16); 72%32-dword phase -> 2-way (free, m136)

__global__ __launch_bounds__(256) void gemm_bf16(
    const u16* __restrict__ A, long lda,
    const u16* __restrict__ B, long ldb,
    u16* __restrict__ out, long ldOut,
    int K,
    const int* __restrict__ rowIdx, int idxMode, int mClamp,
    int mValid, int nValid, int nStore,
    const float* __restrict__ bias, int act, float slope,
    const u16* __restrict__ qbuf, const float* __restrict__ auxF,
    float* __restrict__ dotOut)
{
  // smem: staging As (8 KB) + Bs (8 KB) carved from the 36.9 KB epilogue buffer
  __shared__ __align__(16) u16 smem[4 * 64 * EPS];
  u16* As = smem;            // BM*BK = 4096 u16
  u16* Bs = smem + BM * BK;  // BN*BK = 4096 u16
  const int tid  = threadIdx.x;
  const int wave = tid >> 6, lane = tid & 63;
  const int wr = (wave >> 1) * 64, wc = (wave & 1) * 64;
  const int fr = lane & 15, fq = lane >> 4;
  const long bm = (long)blockIdx.x * BM, bn = (long)blockIdx.y * BN;

  // staging: wave stages rows [wave*32, +32) of A and B as 2 chunks of 16 rows;
  // chunk = 64 lanes x 16B; lane i -> row +i/4, u16 col (i&3)*8.
  const int srow = wave * 32;
  const int kc = (lane & 3) * 8;
  long a0[2], a1[2], boff[2];
  #pragma unroll
  for (int h = 0; h < 2; ++h) {
    long gmRow = bm + srow + h * 16 + (lane >> 2);
    long b0, b1;
    if (idxMode == 0) {
      long gm = (gmRow >= mClamp) ? (mClamp - 1) : gmRow;   // values unused (store-guarded)
      b0 = gm * lda; b1 = b0;
    } else if (idxMode == 2) {
      b0 = (long)rowIdx[2 * gmRow] * lda; b1 = b0;
    } else if (idxMode == 3) {
      b0 = (long)rowIdx[2 * gmRow + 1] * lda; b1 = b0;
    } else { // 4: dual
      b0 = (long)rowIdx[2 * gmRow] * lda;
      b1 = (long)rowIdx[2 * gmRow + 1] * lda - 224;
    }
    a0[h] = b0 + kc; a1[h] = b1 + kc;
    boff[h] = (bn + srow + h * 16 + (lane >> 2)) * ldb + kc;
  }

  fx4 zero4 = {0.f, 0.f, 0.f, 0.f};
  fx4 acc[4][4];
  #pragma unroll
  for (int i = 0; i < 4; ++i)
    #pragma unroll
    for (int j = 0; j < 4; ++j) acc[i][j] = zero4;

  for (int k0 = 0; k0 < K; k0 += BK) {
    __syncthreads();                     // prev tile's ds_reads done
    const bool lo = (k0 + kc) < 224;
    #pragma unroll
    for (int h = 0; h < 2; ++h) {
      const long ao = (idxMode == 4) ? (lo ? a0[h] : a1[h]) : a0[h];
      gload16(A + ao + k0, &As[(srow + h * 16) * BK]);
      gload16(B + boff[h] + k0, &Bs[(srow + h * 16) * BK]);
    }
    __syncthreads();                     // staging complete (vmcnt drained)
    bf8 aF[4], bF[4];
    #pragma unroll
    for (int mt = 0; mt < 4; ++mt) aF[mt] = *(const bf8*)&As[(wr + mt * 16 + fr) * BK + fq * 8];
    #pragma unroll
    for (int nt = 0; nt < 4; ++nt) bF[nt] = *(const bf8*)&Bs[(wc + nt * 16 + fr) * BK + fq * 8];
    #pragma unroll
    for (int mt = 0; mt < 4; ++mt)
      #pragma unroll
      for (int nt = 0; nt < 4; ++nt)
        acc[mt][nt] = __builtin_amdgcn_mfma_f32_16x16x32_bf16(aF[mt], bF[nt], acc[mt][nt], 0, 0, 0);
  }

  // C/D layout: col=lane&15, row=(lane>>4)*4+reg  [m89-verified]
  if (act == 3 || act == 4) {
    #pragma unroll
    for (int mt = 0; mt < 4; ++mt) {
      #pragma unroll
      for (int r = 0; r < 4; ++r) {
        const long gm = bm + wr + mt * 16 + fq * 4 + r;
        float p = 0.f;
        #pragma unroll
        for (int nt = 0; nt < 4; ++nt) {
          const long gn = bn + wc + nt * 16 + fr;
          float v = acc[mt][nt][r] + bias[gn];
          if (act == 3) p += v * bf2f(qbuf[gm * 128 + gn]);
          else { v = (v >= 0.f) ? v : v * slope; p += v * auxF[gn]; }
        }
        p += __shfl_xor(p, 1, 64); p += __shfl_xor(p, 2, 64);
        p += __shfl_xor(p, 4, 64); p += __shfl_xor(p, 8, 64);
        if (fr == 0 && gm < mValid)
          atomicAdd(&dotOut[gm], (act == 3) ? p * 0.07071067811865475f : p);  // 1/sqrt(200)
      }
    }
    return;
  }

  // store epilogue: wave tile (64x64) -> private LDS region -> 16B vector stores
  __syncthreads();                       // all ds_reads of As/Bs complete before reuse
  u16* ep = smem + wave * (64 * EPS);
  #pragma unroll
  for (int mt = 0; mt < 4; ++mt) {
    #pragma unroll
    for (int r = 0; r < 4; ++r) {
      const int lr = mt * 16 + fq * 4 + r;
      const long gm = bm + wr + lr;
      const float attaV = (act == 5) ? dotOut[gm] : 0.f;
      #pragma unroll
      for (int nt = 0; nt < 4; ++nt) {
        const long gn = bn + wc + nt * 16 + fr;
        float v = 0.f;
        if (gn < nValid) {
          v = acc[mt][nt][r];
          if (bias) v += bias[gn];
          if (act == 1) v = tanhf(v);
          else if (act == 5) { v += attaV * auxF[gn]; v = (v >= 0.f) ? v : v * slope; }
        }
        ep[lr * EPS + nt * 16 + fr] = f2bf(v);
      }
    }
  }
  // wave-local readback (compiler inserts lgkmcnt waits); 8 dwordx4 stores per lane
  #pragma unroll
  for (int it = 0; it < 8; ++it) {
    const int lr = it * 8 + (lane >> 3);
    const int lc = (lane & 7) * 8;
    const long gm = bm + wr + lr;
    const long gn = bn + wc + lc;
    if (gm < mValid && gn + 7 < nStore)
      *(bf8*)(out + gm * ldOut + gn) = *(const bf8*)&ep[lr * EPS + lc];
  }
}

// ---------- sorted-CSR edge aggregation ----------
__global__ void hist_kernel(const int* __restrict__ ei, int* __restrict__ cnt) {
  int e = blockIdx.x * 256 + threadIdx.x;
  if (e < N_EDGE) atomicAdd(&cnt[ei[N_EDGE + e]], 1);
}
__global__ void scanA_kernel(const int* __restrict__ cnt, int* __restrict__ offs,
                             int* __restrict__ blockSums) {
  __shared__ int s[256];
  int gid = blockIdx.x * 256 + threadIdx.x;
  int v = (gid < N_ENT) ? cnt[gid] : 0;
  s[threadIdx.x] = v;
  __syncthreads();
  for (int off = 1; off < 256; off <<= 1) {
    int t = (threadIdx.x >= off) ? s[threadIdx.x - off] : 0;
    __syncthreads();
    s[threadIdx.x] += t;
    __syncthreads();
  }
  if (gid < N_ENT) offs[gid] = s[threadIdx.x] - v;
  if (threadIdx.x == 255) blockSums[blockIdx.x] = s[255];
}
__global__ void scanB_kernel(const int* __restrict__ blockSums, int* __restrict__ blockOffs) {
  __shared__ int s[512];
  int v = (threadIdx.x < NB_SCAN) ? blockSums[threadIdx.x] : 0;
  s[threadIdx.x] = v;
  __syncthreads();
  for (int off = 1; off < 512; off <<= 1) {
    int t = (threadIdx.x >= off) ? s[threadIdx.x - off] : 0;
    __syncthreads();
    s[threadIdx.x] += t;
    __syncthreads();
  }
  if (threadIdx.x < NB_SCAN) blockOffs[threadIdx.x] = s[threadIdx.x] - v;
}
__global__ void scanC_kernel(int* __restrict__ offs, const int* __restrict__ blockOffs) {
  int gid = blockIdx.x * 256 + threadIdx.x;
  if (gid < N_ENT) offs[gid] += blockOffs[blockIdx.x];
}
__global__ void place_kernel(const int* __restrict__ ei, const int* __restrict__ et,
                             const int* __restrict__ offs, int* __restrict__ cursor,
                             int* __restrict__ sortedSrc, int* __restrict__ sortedT) {
  int e = blockIdx.x * 256 + threadIdx.x;
  if (e >= N_EDGE) return;
  int dst = ei[N_EDGE + e];
  int pos = offs[dst] + atomicAdd(&cursor[dst], 1);
  sortedSrc[pos] = ei[e];
  sortedT[pos]   = et[e];
}
// wave-per-entity, float4: A1 row = [segsum(ent[src]-rel[t])*rsqrt(max(deg,1)) | ent_emb[r] | 0]
__global__ void agg_A1_kernel(const int* __restrict__ offs, const int* __restrict__ cnt,
                              const int* __restrict__ sortedSrc, const int* __restrict__ sortedT,
                              const float* __restrict__ ent_emb, const float* __restrict__ rel_emb,
                              u16* __restrict__ A1) {
  const int r = blockIdx.x * 4 + (threadIdx.x >> 6);
  if (r >= N_ENT) return;
  const int lane = threadIdx.x & 63;
  const int beg = offs[r], n = cnt[r];
  u16* row = A1 + (size_t)r * 416;
  if (lane < 50) {
    float4 a = {0.f, 0.f, 0.f, 0.f};
    for (int e = 0; e < n; ++e) {
      const int s = sortedSrc[beg + e], t = sortedT[beg + e];
      float4 x = ((const float4*)(ent_emb + (size_t)s * EDIM))[lane];
      float4 y = ((const float4*)(rel_emb + (size_t)t * EDIM))[lane];
      a.x += x.x - y.x; a.y += x.y - y.y; a.z += x.z - y.z; a.w += x.w - y.w;
    }
    const float nm = rsqrtf(fmaxf((float)n, 1.f));
    u64 p = (u64)f2bf(a.x * nm) | ((u64)f2bf(a.y * nm) << 16)
          | ((u64)f2bf(a.z * nm) << 32) | ((u64)f2bf(a.w * nm) << 48);
    *(u64*)(row + 4 * lane) = p;
    float4 e = ((const float4*)(ent_emb + (size_t)r * EDIM))[lane];
    u64 q = (u64)f2bf(e.x) | ((u64)f2bf(e.y) << 16)
          | ((u64)f2bf(e.z) << 32) | ((u64)f2bf(e.w) << 48);
    *(u64*)(row + 200 + 4 * lane) = q;
  }
  if (lane < 16) row[400 + lane] = 0;
}

// ---------- builders / precomputes ----------
__global__ void build_B1T(const float* __restrict__ W, const float* __restrict__ W_loop,
                          u16* __restrict__ B1T)
{
  int idx = blockIdx.x * 256 + threadIdx.x;
  if (idx >= 256 * 416) return;
  int n = idx / 416, k = idx % 416;
  float v = 0.f;
  if (n < 200) {
    if (k < 200) v = W[k * 200 + n];
    else if (k < 400) v = W_loop[(k - 200) * 200 + n];
  }
  B1T[idx] = f2bf(v);
}
__global__ void all_rel_kernel(const float* __restrict__ rel_emb, const float* __restrict__ W_rel,
                               float* __restrict__ all_rel)
{
  int r = blockIdx.x, c = threadIdx.x;
  if (c >= 200) return;
  const float* re = rel_emb + r * 200;
  float a = 0.f;
  for (int k = 0; k < 200; ++k) a += re[k] * W_rel[k * 200 + c];
  all_rel[r * 200 + c] = a;
}
// PQ[sel][m][n] = sum_r all_rel[r][sel*100+m] * w1[401+r][n]
__global__ void pq_kernel(const float* __restrict__ all_rel, const float* __restrict__ w1,
                          float* __restrict__ PQ) {
  int idx = blockIdx.x * 256 + threadIdx.x;
  if (idx >= 2 * 100 * 2048) return;
  int n = idx & 2047, m = (idx >> 11) % 100, sel = idx / 204800;
  float a = 0.f;
  for (int r = 0; r < 474; ++r)
    a += all_rel[r * 200 + sel * 100 + m] * w1[(size_t)(401 + r) * 2048 + n];
  PQ[idx] = a;
}
// P2[sel][k][n] = sum_m trans_w[k][m] * PQ[sel][m][n]
__global__ void p2_kernel(const float* __restrict__ trans_w, const float* __restrict__ PQ,
                          float* __restrict__ P2) {
  int idx = blockIdx.x * 256 + threadIdx.x;
  if (idx >= 2 * 200 * 2048) return;
  int n = idx & 2047, k = (idx >> 11) % 200, sel = idx / 409600;
  const float* pq = PQ + sel * 204800;
  float a = 0.f;
  for (int m = 0; m < 100; ++m) a += trans_w[k * 100 + m] * pq[m * 2048 + n];
  P2[idx] = a;
}
// W1eff [2048][448] B-layout: k<200: w1[k][n]+P2h ; 224<=k<424: w1[200+kk][n]-P2t ; else 0
__global__ void w1eff_kernel(const float* __restrict__ w1, const float* __restrict__ P2,
                             u16* __restrict__ W1eff) {
  int idx = blockIdx.x * 256 + threadIdx.x;
  if (idx >= 2048 * 448) return;
  int n = idx / 448, k = idx % 448;
  float v = 0.f;
  if (k < 200) v = w1[(size_t)k * 2048 + n] + P2[(size_t)k * 2048 + n];
  else if (k >= 224 && k < 424) {
    int kk = k - 224;
    v = w1[(size_t)(200 + kk) * 2048 + n] - P2[409600 + (size_t)kk * 2048 + n];
  }
  W1eff[idx] = f2bf(v);
}
__global__ void b1eff_kernel(const float* __restrict__ b1, const float* __restrict__ trans_b,
                             const float* __restrict__ PQ, float* __restrict__ b1eff) {
  int n = blockIdx.x * 256 + threadIdx.x;
  if (n >= 2048) return;
  float a = b1[n];
  for (int m = 0; m < 100; ++m)
    a += trans_b[m] * (PQ[m * 2048 + n] - PQ[204800 + m * 2048 + n]);
  b1eff[n] = a;
}
// qw2T/kw2T [128][224] B-layout: row j, col k<200: sum_m trans_w[k][m]*{q,k}_w[m][j]
__global__ void qkw2_kernel(const float* __restrict__ trans_w, const float* __restrict__ q_w,
                            const float* __restrict__ k_w, u16* __restrict__ qw2T,
                            u16* __restrict__ kw2T) {
  int idx = blockIdx.x * 256 + threadIdx.x;
  if (idx >= 128 * 224) return;
  int j = idx / 224, k = idx % 224;
  float a = 0.f, b = 0.f;
  if (k < 200)
    for (int m = 0; m < 100; ++m) {
      float t = trans_w[k * 100 + m];
      a += t * q_w[m * 128 + j];
      b += t * k_w[m * 128 + j];
    }
  qw2T[idx] = f2bf(a);
  kw2T[idx] = f2bf(b);
}
__global__ void qkb2_kernel(const float* __restrict__ q_b, const float* __restrict__ k_b,
                            const float* __restrict__ trans_b, const float* __restrict__ q_w,
                            const float* __restrict__ k_w, float* __restrict__ qb2,
                            float* __restrict__ kb2) {
  int j = threadIdx.x;
  if (j >= 128) return;
  float a = q_b[j], b = k_b[j];
  for (int m = 0; m < 100; ++m) {
    a += trans_b[m] * q_w[m * 128 + j];
    b += trans_b[m] * k_w[m * 128 + j];
  }
  qb2[j] = a; kb2[j] = b;
}
__global__ void build_w2T(const float* __restrict__ w2, u16* __restrict__ w2T)
{
  long idx = (long)blockIdx.x * 256 + threadIdx.x;
  if (idx >= (long)512 * 2048) return;
  int n = (int)(idx / 2048), k = (int)(idx % 2048);
  w2T[idx] = f2bf(w2[(size_t)k * 512 + n]);
}
__global__ void sigmoid_kernel(const float* __restrict__ logit, const float* __restrict__ b3,
                               float* __restrict__ out) {
  int i = blockIdx.x * 256 + threadIdx.x;
  if (i >= N_TEST) return;
  out[i] = 1.f / (1.f + __expf(-(logit[i] + b3[0])));
}

// ---------- host ----------
extern "C" void kernel_launch(void* const* d_in, const int* in_sizes, int n_in,
                              void* d_out, int out_size, void* d_ws, size_t ws_size,
                              hipStream_t stream)
{
  (void)in_sizes; (void)n_in; (void)out_size;
  const int*   edge_index = (const int*)d_in[0];
  const int*   edge_type  = (const int*)d_in[1];
  const int*   toTest     = (const int*)d_in[2];
  const float* ent_emb    = (const float*)d_in[3];
  const float* rel_emb    = (const float*)d_in[4];
  const float* W          = (const float*)d_in[5];
  const float* W_loop     = (const float*)d_in[6];
  const float* W_rel      = (const float*)d_in[7];
  const float* trans_w    = (const float*)d_in[8];
  const float* trans_b    = (const float*)d_in[9];
  const float* q_w        = (const float*)d_in[10];
  const float* q_b        = (const float*)d_in[11];
  const float* k_w        = (const float*)d_in[12];
  const float* k_b        = (const float*)d_in[13];
  const float* w1         = (const float*)d_in[14];
  const float* b1         = (const float*)d_in[15];
  const float* w2         = (const float*)d_in[16];
  const float* b2         = (const float*)d_in[17];
  const float* w3         = (const float*)d_in[18];
  const float* b3         = (const float*)d_in[19];
  float* out = (float*)d_out;

  // ---- workspace layout (lifetime overlays) ----
  unsigned char* ws = (unsigned char*)d_ws;
  float* atta    = (float*)(ws + 0);            //   524,288
  float* logit   = (float*)(ws + 524288);       //   524,288
  float* allrel  = (float*)(ws + 1048576);      //   379,392 (474*200*4 pad)
  u16*   B1T     = (u16*)  (ws + 1427968);      //   212,992
  u16*   W1eff   = (u16*)  (ws + 1640960);      // 1,835,008 (2048*448*2)
  u16*   qw2T    = (u16*)  (ws + 3475968);      //    57,344
  u16*   kw2T    = (u16*)  (ws + 3533312);      //    57,344
  float* b1eff   = (float*)(ws + 3590656);      //     8,192
  float* qb2     = (float*)(ws + 3598848);      //     1,024 (pad)
  float* kb2     = (float*)(ws + 3599872);      //     1,024 (pad)
  u16*   w2T     = (u16*)  (ws + 3600896);      // 2,097,152
  const size_t X_base = 5698048;
  u16*   all_ent = (u16*)  (ws + X_base);                  // 44,800,000
  u16*   Qbuf    = (u16*)  (ws + X_base + 44800000);       // 33,554,432
  const size_t Y_base = 84052480;
  u16*   A1      = (u16*)  (ws + Y_base);       // 83,200,000 (dead after GEMM1)
  const size_t Z_base = 167252480;

  // Z scratch (dead after precomputes, before h1 is written)
  int*   cnt       = (int*)  (ws + Z_base);
  int*   offs      = (int*)  (ws + Z_base + 400000);
  int*   cursor    = (int*)  (ws + Z_base + 800000);
  int*   blockSums = (int*)  (ws + Z_base + 1200000);
  int*   blockOffs = (int*)  (ws + Z_base + 1202048);
  int*   sortedSrc = (int*)  (ws + Z_base + 1204096);
  int*   sortedT   = (int*)  (ws + Z_base + 3204096);
  float* PQ        = (float*)(ws + Z_base + 5204096);   // 1,638,400
  float* P2        = (float*)(ws + Z_base + 6842496);   // 3,276,800 -> ends Z+10,119,296

  int CH;
  if      (Z_base + (size_t)131072 * 4096 <= ws_size) CH = 131072;
  else if (Z_base + (size_t)65536  * 4096 <= ws_size) CH = 65536;
  else if (Z_base + (size_t)32768  * 4096 <= ws_size) CH = 32768;
  else if (Z_base + (size_t)16384  * 4096 <= ws_size) CH = 16384;
  else if (Z_base + (size_t)8192   * 4096 <= ws_size) CH = 8192;
  else return;
  u16* h1 = (u16*)(ws + Z_base);                 // CH*2048*2 (overlays dead scratch)
  const int NC = N_TEST / CH;

  hipMemsetAsync(cnt, 0, 400000, stream);
  hipMemsetAsync(cursor, 0, 400000, stream);
  hipMemsetAsync(atta, 0, 524288, stream);
  hipMemsetAsync(logit, 0, 524288, stream);

  // phase 1: CSR aggregation -> A1
  hist_kernel<<<(N_EDGE + 255) / 256, 256, 0, stream>>>(edge_index, cnt);
  scanA_kernel<<<NB_SCAN, 256, 0, stream>>>(cnt, offs, blockSums);
  scanB_kernel<<<1, 512, 0, stream>>>(blockSums, blockOffs);
  scanC_kernel<<<NB_SCAN, 256, 0, stream>>>(offs, blockOffs);
  place_kernel<<<(N_EDGE + 255) / 256, 256, 0, stream>>>(edge_index, edge_type, offs, cursor,
                                                         sortedSrc, sortedT);
  agg_A1_kernel<<<(N_ENT + 3) / 4, 256, 0, stream>>>(offs, cnt, sortedSrc, sortedT,
                                                     ent_emb, rel_emb, A1);
  build_B1T<<<(256 * 416) / 256, 256, 0, stream>>>(W, W_loop, B1T);

  // all_ent = tanh([agg*norm | ent] @ [W ; W_loop]) -> bf16 [100000][224]
  gemm_bf16<<<dim3(782, 2), 256, 0, stream>>>(A1, 416, B1T, 416, all_ent, AE_LD,
      416, nullptr, 0, N_ENT, N_ENT, 200, AE_LD, nullptr, 1, 0.f, nullptr, nullptr, nullptr);

  // phase 2: folded-weight precomputes (f32; PQ/P2 die here)
  all_rel_kernel<<<474, 256, 0, stream>>>(rel_emb, W_rel, allrel);
  pq_kernel<<<(2 * 100 * 2048) / 256, 256, 0, stream>>>(allrel, w1, PQ);
  p2_kernel<<<(2 * 200 * 2048) / 256, 256, 0, stream>>>(trans_w, PQ, P2);
  w1eff_kernel<<<(2048 * 448) / 256, 256, 0, stream>>>(w1, P2, W1eff);
  b1eff_kernel<<<8, 256, 0, stream>>>(b1, trans_b, PQ, b1eff);
  qkw2_kernel<<<(128 * 224) / 256, 256, 0, stream>>>(trans_w, q_w, k_w, qw2T, kw2T);
  qkb2_kernel<<<1, 128, 0, stream>>>(q_b, k_b, trans_b, q_w, k_w, qb2, kb2);
  build_w2T<<<(512 * 2048) / 256, 256, 0, stream>>>(w2, w2T);

  // phase 3: atta = ((te0@qw2+qb2) . (te1@kw2+kb2)) / sqrt(200)  (gathered from all_ent)
  gemm_bf16<<<dim3(1024, 1), 256, 0, stream>>>(all_ent, AE_LD, qw2T, AE_LD, Qbuf, 128,
      AE_LD, toTest, 2, 0, N_TEST, 128, 128, qb2, 0, 0.f, nullptr, nullptr, nullptr);
  gemm_bf16<<<dim3(1024, 1), 256, 0, stream>>>(all_ent, AE_LD, kw2T, AE_LD, nullptr, 0,
      AE_LD, toTest, 3, 0, N_TEST, 128, 128, kb2, 3, 0.f, Qbuf, nullptr, atta);

  // phase 4: per-chunk  h1 = lrelu(dual[te0|te1] @ W1eff + atta*w1[400,:] + b1eff)
  //          logit += rowdot(lrelu(h1 @ w2T + b2), w3)  ;  then sigmoid
  for (int c = 0; c < NC; ++c) {
    gemm_bf16<<<dim3(CH / 128, 16), 256, 0, stream>>>(all_ent, AE_LD, W1eff, 448, h1, 2048,
        448, toTest + (size_t)c * CH * 2, 4, 0, CH, 2048, 2048, b1eff, 5, 0.0001f,
        nullptr, w1 + (size_t)400 * 2048, atta + (size_t)c * CH);
    gemm_bf16<<<dim3(CH / 128, 4), 256, 0, stream>>>(h1, 2048, w2T, 2048, nullptr, 0,
        2048, nullptr, 0, CH, CH, 512, 512, b2, 4, 0.001f,
        nullptr, w3, logit + (size_t)c * CH);
  }
  sigmoid_kernel<<<N_TEST / 256, 256, 0, stream>>>(logit, b3, out);
}